// Round 16
// baseline (263.677 us; speedup 1.0000x reference)
//
#include <hip/hip_runtime.h>

// ---------------------------------------------------------------------------
// net_39041252721195: SplineConv(1->2) + ELU + BN + SplineConv(2->4) + BN
//                     + 4x4 grid max-pool + FC(64->4)
// K=2, DIM=3: pseudo in [0,1) => lo==0, idx==b. Basis weights = trilinear.
//
// Round 26: R25 passed 253.8us. agg2 fixed (factorization); now fused_agg1
// 42us at VALUBusy 19% / FETCH 20.6MB / occupancy 17% -- latency-bound:
// grid is 512 blocks = 2 blocks/CU, nothing hides the serial x-gather
// chain. Fix: 256-node buckets (NBUCK=1024, dst>>8) -> agg kernels run
// 1024 blocks = 4/CU with ~39-40KB LDS (4 co-resident fit). Buckets now
// single-phase: rescatter scans regs once (18 vs 80 iters), 2 fewer
// barriers, REGN 40->18. Sort re-parameterized to 1024 bins (scatter scan
// 4 bins/thread; runs shorten 128B->64B, small WRITE uptick accepted).
// ---------------------------------------------------------------------------

#define TPB 256
#define LNODE 256                   // nodes per bucket
#define BUCK_SHIFT 8
#define NBUCK 1024                  // N / 256 (N = 262144)
#define BPART 512                   // partition blocks for bucket hist/scatter
#define REGN 18                     // records staged per thread (cap 4608/bucket)
#define SCAP 4608                   // LDS stage cap per bucket (mean 4096, 8 sd)
#define CHUNK 4096                  // scatter chunk (block owns 8192 = 2 chunks)
#define EPT 16                      // edges per thread per chunk

typedef unsigned long long u64;
typedef unsigned int u32;
typedef unsigned short u16;

__device__ __forceinline__ void basis_weights(float f0, float f1, float f2, float w[8]) {
    float g0 = 1.f - f0, g1 = 1.f - f1, g2 = 1.f - f2;
    w[0] = g0 * g1 * g2;  w[1] = f0 * g1 * g2;
    w[2] = g0 * f1 * g2;  w[3] = f0 * f1 * g2;
    w[4] = g0 * g1 * f2;  w[5] = f0 * g1 * f2;
    w[6] = g0 * f1 * f2;  w[7] = f0 * f1 * f2;
}

__device__ __forceinline__ u64 pack_rec(int src, int dloc, float f0, float f1, float f2) {
    u32 q0 = (u32)(f0 * 4095.f + 0.5f);
    u32 q1 = (u32)(f1 * 4095.f + 0.5f);
    u32 q2 = (u32)(f2 * 4095.f + 0.5f);
    return (u64)(u32)src | ((u64)(u32)dloc << 18)
         | ((u64)q0 << 27) | ((u64)q1 << 39) | ((u64)q2 << 51);
}

// ---- exclusive scan of per-thread sums over 256 threads (shfl + fixup) -----
__device__ __forceinline__ u32 scan_shfl(u32 tsum, u32* wtot, int t) {
    u32 incl = tsum;
#pragma unroll
    for (int o = 1; o < 64; o <<= 1) {
        u32 v = __shfl_up(incl, o, 64);
        if ((t & 63) >= o) incl += v;
    }
    if ((t & 63) == 63) wtot[t >> 6] = incl;
    __syncthreads();
    u32 wbase = 0;
#pragma unroll
    for (int w = 0; w < 4; w++) wbase += (w < (t >> 6)) ? wtot[w] : 0u;
    return wbase + incl - tsum;
}

// ---- bucket sort pass 1: per-block LDS histogram of dst>>8 -----------------
__global__ void hist_kernel(const int* __restrict__ ei, int E,
                            u32* __restrict__ cntArr /* [NBUCK][BPART] */) {
    __shared__ u32 h[NBUCK];              // 4 KB
    for (int i = threadIdx.x; i < NBUCK; i += TPB) h[i] = 0u;
    __syncthreads();
    int ch = (E + BPART - 1) / BPART;
    int s = blockIdx.x * ch;
    int e_end = min(E, s + ch);
    int e = s + threadIdx.x * 4;
    for (; e + 4 <= e_end; e += TPB * 4) {
        int4 d4 = *(const int4*)&ei[E + e];
        atomicAdd(&h[d4.x >> BUCK_SHIFT], 1u);
        atomicAdd(&h[d4.y >> BUCK_SHIFT], 1u);
        atomicAdd(&h[d4.z >> BUCK_SHIFT], 1u);
        atomicAdd(&h[d4.w >> BUCK_SHIFT], 1u);
    }
    for (e = e_end - (e_end - s) % (TPB * 4) + threadIdx.x; e < e_end; e += TPB)
        atomicAdd(&h[ei[E + e] >> BUCK_SHIFT], 1u);
    __syncthreads();
    for (int i = threadIdx.x; i < NBUCK; i += TPB)
        cntArr[i * BPART + blockIdx.x] = h[i];
}

// ---- scan: per-bucket exclusive prefix over BPART values, IN PLACE ---------
__global__ void scanB_kernel(u32* __restrict__ data,
                             u32* __restrict__ totals) {
    __shared__ u32 s[BPART];
    int t = threadIdx.x, g = blockIdx.x;
    u32 v = data[g * BPART + t];
    s[t] = v;
    __syncthreads();
    for (int o = 1; o < BPART; o <<= 1) {
        u32 u = (t >= o) ? s[t - o] : 0u;
        __syncthreads();
        s[t] += u;
        __syncthreads();
    }
    data[g * BPART + t] = s[t] - v;     // exclusive
    if (t == BPART - 1) totals[g] = s[t];
}

// ---- scan of NBUCK bucket totals -> bucket bases (1024 threads) ------------
__global__ void scanbase_kernel(const u32* __restrict__ in,   // [NBUCK]
                                u32* __restrict__ excl) {     // [NBUCK]
    __shared__ u32 s[NBUCK];              // 4 KB
    int t = threadIdx.x;
    u32 v = in[t];
    s[t] = v;
    __syncthreads();
    for (int o = 1; o < NBUCK; o <<= 1) {
        u32 u = (t >= o) ? s[t - o] : 0u;
        __syncthreads();
        s[t] += u;
        __syncthreads();
    }
    excl[t] = s[t] - v;
}

// ---- scatter: chunk-local LDS counting sort -> coalesced stream writes -----
__global__ void __launch_bounds__(TPB)
scatter_kernel(const int* __restrict__ ei,
               const float* __restrict__ attr,
               const u32* __restrict__ bktBase,
               const u32* __restrict__ preArr,
               u64* __restrict__ part1, int E) {
    __shared__ u64 stage[CHUNK];          // 32 KB bucket-grouped records
    __shared__ u16 bid[CHUNK];            // 8 KB bucket id per stage slot
    __shared__ u32 cnt[NBUCK];            // 4 KB per-chunk counts
    __shared__ u32 cbase[NBUCK];          // 4 KB chunk-local bucket bases
    __shared__ u32 gcur[NBUCK];           // 4 KB global cursors
    __shared__ u32 wtot[4];               // wave totals for shfl scan
    int t = threadIdx.x, blk = blockIdx.x;
    for (int i = t; i < NBUCK; i += TPB)
        gcur[i] = bktBase[i] + preArr[i * BPART + blk];
    int ch = (E + BPART - 1) / BPART;     // 8192
    int s0 = blk * ch;
    int e_end = min(E, s0 + ch);
    for (int cs = s0; cs < e_end; cs += CHUNK) {
        int cn = min(CHUNK, e_end - cs);
        for (int i = t; i < NBUCK; i += TPB) cnt[i] = 0u;
        __syncthreads();
        // pass A: vectorized load+pack (4 edges per k-step), rank via LDS atomic
        u64 rec[EPT]; u32 bb[EPT], rk[EPT];
#pragma unroll
        for (int k = 0; k < 4; k++) {
            int e = cs + k * (TPB * 4) + t * 4;
            if (e + 3 < e_end) {
                int4 s4 = *(const int4*)&ei[e];
                int4 d4 = *(const int4*)&ei[E + e];
                float4 a0 = *(const float4*)&attr[3 * e];
                float4 a1 = *(const float4*)&attr[3 * e + 4];
                float4 a2 = *(const float4*)&attr[3 * e + 8];
                int srcs[4] = {s4.x, s4.y, s4.z, s4.w};
                int dsts[4] = {d4.x, d4.y, d4.z, d4.w};
                float f[4][3] = {{a0.x, a0.y, a0.z}, {a0.w, a1.x, a1.y},
                                 {a1.z, a1.w, a2.x}, {a2.y, a2.z, a2.w}};
#pragma unroll
                for (int j = 0; j < 4; j++) {
                    int m = 4 * k + j;
                    rec[m] = pack_rec(srcs[j], dsts[j] & (LNODE - 1),
                                      f[j][0], f[j][1], f[j][2]);
                    bb[m] = (u32)dsts[j] >> BUCK_SHIFT;
                    rk[m] = atomicAdd(&cnt[bb[m]], 1u);
                }
            } else {
#pragma unroll
                for (int j = 0; j < 4; j++) {
                    int m = 4 * k + j;
                    int ee = e + j;
                    bb[m] = 0xFFFFFFFFu;
                    if (ee < e_end) {
                        rec[m] = pack_rec(ei[ee], ei[E + ee] & (LNODE - 1),
                                          attr[3 * ee], attr[3 * ee + 1],
                                          attr[3 * ee + 2]);
                        bb[m] = (u32)ei[E + ee] >> BUCK_SHIFT;
                        rk[m] = atomicAdd(&cnt[bb[m]], 1u);
                    }
                }
            }
        }
        __syncthreads();
        // shfl scan of 1024 counts (4 bins/thread) -> chunk-local bases
        u32 c0 = cnt[4 * t], c1 = cnt[4 * t + 1];
        u32 c2 = cnt[4 * t + 2], c3 = cnt[4 * t + 3];
        u32 ex = scan_shfl(c0 + c1 + c2 + c3, wtot, t);
        cbase[4 * t] = ex;
        cbase[4 * t + 1] = ex + c0;
        cbase[4 * t + 2] = ex + c0 + c1;
        cbase[4 * t + 3] = ex + c0 + c1 + c2;
        __syncthreads();
        // pass B: LDS scatter into bucket-grouped order
#pragma unroll
        for (int m = 0; m < EPT; m++) {
            if (bb[m] != 0xFFFFFFFFu) {
                u32 p = cbase[bb[m]] + rk[m];
                stage[p] = rec[m];
                bid[p] = (u16)bb[m];
            }
        }
        __syncthreads();
        // pass C: i-ordered write-out -> contiguous bursts per bucket run
        for (int i = t; i < cn; i += TPB) {
            u32 b = (u32)bid[i];
            part1[gcur[b] + ((u32)i - cbase[b])] = stage[i];
        }
        __syncthreads();
        // pass D: advance cursors
        gcur[4 * t] += c0;
        gcur[4 * t + 1] += c1;
        gcur[4 * t + 2] += c2;
        gcur[4 * t + 3] += c3;
        __syncthreads();
    }
}

// ---- layer 1: single-phase 256-node bucket, reg-staged + LDS stage ---------
__global__ void __launch_bounds__(TPB)
fused_agg1_kernel(const u64* __restrict__ part1,
                  const u32* __restrict__ bktBase,
                  const u32* __restrict__ bktTot,
                  const float* __restrict__ x,
                  const float* __restrict__ W1,      // [8][1][2] = 16 floats
                  u32* __restrict__ deg,
                  u32* __restrict__ off,
                  float* __restrict__ h1,
                  float* __restrict__ accum /* sum[2], sq[2] */) {
    __shared__ u64 stage[SCAP];            // 36.9 KB node-ordered bucket
    __shared__ u32 hist[LNODE];            // 1 KB counts -> cursors (local)
    __shared__ u32 obase[LNODE];           // 1 KB local segment starts
    __shared__ u32 wtot[4];
    __shared__ float rbuf[4][4];
    int t = threadIdx.x, g = blockIdx.x;
    u32 s = bktBase[g], n_e = bktTot[g];
    if (n_e > (u32)SCAP) n_e = (u32)SCAP;  // 8-sd safety clamp
    hist[t] = 0u;
    // register staging: one coalesced read of the bucket window
    u64 rec[REGN];
#pragma unroll
    for (int k = 0; k < REGN; k++) {
        u32 i = (u32)t + (u32)k * TPB;
        rec[k] = (i < n_e) ? part1[s + i] : 0ull;
    }
    __syncthreads();
    // count local node ids (from registers)
#pragma unroll
    for (int k = 0; k < REGN; k++) {
        u32 i = (u32)t + (u32)k * TPB;
        if (i < n_e)
            atomicAdd(&hist[(u32)(rec[k] >> 18) & (LNODE - 1)], 1u);
    }
    __syncthreads();
    // scan 256 counts (1 bin/thread) -> local offsets
    u32 c = hist[t];
    u32 ex = scan_shfl(c, wtot, t);
    obase[t] = ex;
    int n = (g << BUCK_SHIFT) + t;
    deg[n] = c; off[n] = s + ex;
    hist[t] = ex;                          // local cursor
    __syncthreads();
    // rescatter all records from registers into LDS stage (node order)
#pragma unroll
    for (int k = 0; k < REGN; k++) {
        u32 i = (u32)t + (u32)k * TPB;
        if (i < n_e) {
            u32 loc = (u32)(rec[k] >> 18) & (LNODE - 1);
            u32 pos = atomicAdd(&hist[loc], 1u);
            stage[pos] = rec[k];
        }
    }
    __syncthreads();
    // aggregate node t from LDS: S[b] = sum_e w_b * x_e
    u32 st = obase[t], en = hist[t];       // cursor = segment end
    u32 d = en - st;
    float S[8];
#pragma unroll
    for (int b = 0; b < 8; b++) S[b] = 0.f;
    for (u32 j = st; j < en; ++j) {
        u64 r = stage[j];
        float xv = x[(u32)r & 0x3FFFFu];
        float f0 = (float)((u32)(r >> 27) & 0xFFFu) * (1.f / 4095.f);
        float f1 = (float)((u32)(r >> 39) & 0xFFFu) * (1.f / 4095.f);
        float f2 = (float)((u32)(r >> 51) & 0xFFFu) * (1.f / 4095.f);
        float w[8];
        basis_weights(f0, f1, f2, w);
#pragma unroll
        for (int b = 0; b < 8; b++) S[b] += w[b] * xv;
    }
    float s0 = 0.f, s1 = 0.f;
#pragma unroll
    for (int b = 0; b < 8; b++) {
        s0 += S[b] * W1[2 * b];
        s1 += S[b] * W1[2 * b + 1];
    }
    float cm = d > 1u ? (float)d : 1.f;
    float a = s0 / cm, b = s1 / cm;
    a = a > 0.f ? a : (__expf(a) - 1.f);   // ELU
    b = b > 0.f ? b : (__expf(b) - 1.f);
    *(float2*)&h1[2 * n] = make_float2(a, b);
    // BN1 statistics
    float ts0 = a, ts1 = b, tq0 = a * a, tq1 = b * b;
#pragma unroll
    for (int o = 32; o > 0; o >>= 1) {
        ts0 += __shfl_down(ts0, o, 64);
        ts1 += __shfl_down(ts1, o, 64);
        tq0 += __shfl_down(tq0, o, 64);
        tq1 += __shfl_down(tq1, o, 64);
    }
    int wv = t >> 6;
    if ((t & 63) == 0) {
        rbuf[wv][0] = ts0; rbuf[wv][1] = ts1;
        rbuf[wv][2] = tq0; rbuf[wv][3] = tq1;
    }
    __syncthreads();
    if (t < 4) {
        float v = rbuf[0][t] + rbuf[1][t] + rbuf[2][t] + rbuf[3][t];
        atomicAdd(&accum[t], v);
    }
}

// ---- BN params: scale = gamma*rsqrt(var+eps); shift = beta - mu*scale ------
__global__ void bnparams_kernel(const float* __restrict__ accum,
                                const float* __restrict__ gamma,
                                const float* __restrict__ beta,
                                float* __restrict__ params, int C, float invN) {
    int c = threadIdx.x;
    if (c < C) {
        float mu  = accum[c] * invN;
        float var = accum[C + c] * invN - mu * mu;
        float sc  = gamma[c] * rsqrtf(var + 1e-5f);
        params[c] = sc;
        params[C + c] = beta[c] - mu * sc;
    }
}

// ---- layer 2: single-phase 256-node bucket; factorized inner loop ----------
__global__ void __launch_bounds__(TPB)
agg2_kernel(const u64* __restrict__ part1,
            const u32* __restrict__ bktBase,
            const u32* __restrict__ bktTot,
            const u32* __restrict__ off,
            const u32* __restrict__ deg,
            const float* __restrict__ h1,
            const float* __restrict__ W2,        // [8][2][4] = 64 floats
            const float* __restrict__ params,    // sc1[2], sh1[2]
            float* __restrict__ h2,
            float* __restrict__ accum /* sum[4], sq[4] */) {
    __shared__ u64 stage[SCAP];             // 36.9 KB
    __shared__ u32 hist[LNODE];             // 1 KB local cursors
    __shared__ u32 obase[LNODE];            // 1 KB local starts
    __shared__ float rbuf[4][8];
    int t = threadIdx.x, g = blockIdx.x;
    u32 s = bktBase[g], n_e = bktTot[g];
    if (n_e > (u32)SCAP) n_e = (u32)SCAP;
    int n = (g << BUCK_SHIFT) + t;
    u32 o = off[n] - s;                    // local
    u32 dd = deg[n];
    obase[t] = o;
    hist[t] = o;                           // cursor init
    // register staging: one coalesced read
    u64 rec[REGN];
#pragma unroll
    for (int k = 0; k < REGN; k++) {
        u32 i = (u32)t + (u32)k * TPB;
        rec[k] = (i < n_e) ? part1[s + i] : 0ull;
    }
    float sc0 = params[0], sc1 = params[1], sh0 = params[2], sh1 = params[3];
    __syncthreads();
    // rescatter into node order
#pragma unroll
    for (int k = 0; k < REGN; k++) {
        u32 i = (u32)t + (u32)k * TPB;
        if (i < n_e) {
            u32 loc = (u32)(rec[k] >> 18) & (LNODE - 1);
            u32 pos = atomicAdd(&hist[loc], 1u);
            stage[pos] = rec[k];
        }
    }
    __syncthreads();
    // aggregate node t: factorized Sa[b] = sum w_b*a, Sb[b] = sum w_b*b
    u32 st = obase[t], en = st + dd;
    if (en > n_e) en = n_e;
    float Sa[8], Sb[8];
#pragma unroll
    for (int b = 0; b < 8; b++) { Sa[b] = 0.f; Sb[b] = 0.f; }
    for (u32 j = st; j < en; ++j) {
        u64 r = stage[j];
        float2 hv = *(const float2*)&h1[2 * ((u32)r & 0x3FFFFu)];
        float a = hv.x * sc0 + sh0;
        float b = hv.y * sc1 + sh1;
        float f0 = (float)((u32)(r >> 27) & 0xFFFu) * (1.f / 4095.f);
        float f1 = (float)((u32)(r >> 39) & 0xFFFu) * (1.f / 4095.f);
        float f2 = (float)((u32)(r >> 51) & 0xFFFu) * (1.f / 4095.f);
        float w[8];
        basis_weights(f0, f1, f2, w);
#pragma unroll
        for (int bb = 0; bb < 8; bb++) {
            Sa[bb] += w[bb] * a;
            Sb[bb] += w[bb] * b;
        }
    }
    // per-node W2 contraction
    float m0 = 0.f, m1 = 0.f, m2 = 0.f, m3 = 0.f;
#pragma unroll
    for (int bb = 0; bb < 8; bb++) {
        m0 += Sa[bb] * W2[8 * bb + 0] + Sb[bb] * W2[8 * bb + 4];
        m1 += Sa[bb] * W2[8 * bb + 1] + Sb[bb] * W2[8 * bb + 5];
        m2 += Sa[bb] * W2[8 * bb + 2] + Sb[bb] * W2[8 * bb + 6];
        m3 += Sa[bb] * W2[8 * bb + 3] + Sb[bb] * W2[8 * bb + 7];
    }
    float cm = dd > 1u ? (float)dd : 1.f;
    m0 /= cm; m1 /= cm; m2 /= cm; m3 /= cm;
    float4 o4; o4.x = m0; o4.y = m1; o4.z = m2; o4.w = m3;
    *(float4*)&h2[4 * n] = o4;
    // BN2 statistics
    float ts[4] = {m0, m1, m2, m3};
    float tq[4] = {m0 * m0, m1 * m1, m2 * m2, m3 * m3};
#pragma unroll
    for (int o2 = 32; o2 > 0; o2 >>= 1) {
#pragma unroll
        for (int ch = 0; ch < 4; ch++) {
            ts[ch] += __shfl_down(ts[ch], o2, 64);
            tq[ch] += __shfl_down(tq[ch], o2, 64);
        }
    }
    int wv = t >> 6;
    if ((t & 63) == 0) {
#pragma unroll
        for (int ch = 0; ch < 4; ch++) {
            rbuf[wv][ch] = ts[ch];
            rbuf[wv][4 + ch] = tq[ch];
        }
    }
    __syncthreads();
    if (t < 8) {
        float v = rbuf[0][t] + rbuf[1][t] + rbuf[2][t] + rbuf[3][t];
        atomicAdd(&accum[t], v);
    }
}

// ---- pooling: BN2 normalize, grid cluster, ordered-uint atomicMax ----------
__device__ __forceinline__ unsigned enc_float(float v) {
    unsigned u = __float_as_uint(v);
    return (v >= 0.f) ? (u | 0x80000000u) : ~u;
}

__global__ void pool_kernel(const float* __restrict__ h2,
                            const float* __restrict__ pos,
                            const float* __restrict__ params, // scale2[4], shift2[4]
                            unsigned* __restrict__ pooled, int N) {
    __shared__ unsigned lmax[64];
    for (int i = threadIdx.x; i < 64; i += blockDim.x) lmax[i] = 0u;
    __syncthreads();
    float sc[4], sh[4];
#pragma unroll
    for (int c = 0; c < 4; c++) { sc[c] = params[c]; sh[c] = params[4 + c]; }
    int stride = gridDim.x * blockDim.x;
    for (int n = blockIdx.x * blockDim.x + threadIdx.x; n < N; n += stride) {
        float px = pos[2 * n + 0], py = pos[2 * n + 1];
        int cx = (int)floorf(px * (1.f / 25.f));
        int cy = (int)floorf(py * (1.f / 25.f));
        cx = min(max(cx, 0), 3);
        cy = min(max(cy, 0), 3);
        int cl = cx + 4 * cy;
        float4 h = *(const float4*)&h2[4 * n];
        atomicMax(&lmax[4 * cl + 0], enc_float(h.x * sc[0] + sh[0]));
        atomicMax(&lmax[4 * cl + 1], enc_float(h.y * sc[1] + sh[1]));
        atomicMax(&lmax[4 * cl + 2], enc_float(h.z * sc[2] + sh[2]));
        atomicMax(&lmax[4 * cl + 3], enc_float(h.w * sc[3] + sh[3]));
    }
    __syncthreads();
    for (int i = threadIdx.x; i < 64; i += blockDim.x)
        if (lmax[i]) atomicMax(&pooled[i], lmax[i]);
}

// ---- final: decode pooled, FC 64->4 ----------------------------------------
__global__ void final_kernel(const unsigned* __restrict__ pooled,
                             const float* __restrict__ fcw, // [4][64]
                             float* __restrict__ out) {
    __shared__ float p[64];
    int t = threadIdx.x;
    if (t < 64) {
        unsigned u = pooled[t];
        float v = 0.f;
        if (u != 0u) {
            unsigned bits = (u & 0x80000000u) ? (u ^ 0x80000000u) : ~u;
            v = __uint_as_float(bits);
        }
        p[t] = v;
    }
    __syncthreads();
    if (t < 4) {
        float s = 0.f;
        for (int k = 0; k < 64; k++) s += p[k] * fcw[t * 64 + k];
        out[t] = s;
    }
}

// ---------------------------------------------------------------------------
extern "C" void kernel_launch(void* const* d_in, const int* in_sizes, int n_in,
                              void* d_out, int out_size, void* d_ws, size_t ws_size,
                              hipStream_t stream) {
    const float* x      = (const float*)d_in[0];
    const int*   ei     = (const int*)d_in[1];
    const float* attr   = (const float*)d_in[2];
    const float* pos    = (const float*)d_in[3];
    const float* W1     = (const float*)d_in[4];
    const float* W2     = (const float*)d_in[5];
    const float* gamma1 = (const float*)d_in[6];
    const float* beta1  = (const float*)d_in[7];
    const float* gamma2 = (const float*)d_in[8];
    const float* beta2  = (const float*)d_in[9];
    const float* fcw    = (const float*)d_in[10];
    float* out = (float*)d_out;

    const int N = in_sizes[0];       // 262144 = 1024*256
    const int E = in_sizes[2] / 3;   // 4194304

    // workspace layout (~45 MB)
    u64* part1 = (u64*)d_ws;                             // E packed records (bucket order)
    float* base = (float*)(part1 + E);
    float* accum  = base;                                // 12
    float* params = base + 12;                           // 12
    unsigned* pooled = (unsigned*)(base + 24);           // 64
    u32* cntArr  = (u32*)(base + 88);                    // NBUCK*BPART (scanned in place)
    u32* bktTot  = cntArr + (size_t)NBUCK * BPART;       // NBUCK
    u32* bktBase = bktTot + NBUCK;                       // NBUCK
    u32* deg     = bktBase + NBUCK;                      // N
    u32* off     = deg + N;                              // N (global CSR offsets)
    float* h1 = (float*)(off + N);                       // 2N
    float* h2 = h1 + 2 * (size_t)N;                      // 4N

    hipMemsetAsync(base, 0, 88 * sizeof(float), stream);

    hist_kernel<<<BPART, TPB, 0, stream>>>(ei, E, cntArr);
    scanB_kernel<<<NBUCK, BPART, 0, stream>>>(cntArr, bktTot);
    scanbase_kernel<<<1, NBUCK, 0, stream>>>(bktTot, bktBase);
    scatter_kernel<<<BPART, TPB, 0, stream>>>(ei, attr, bktBase, cntArr, part1, E);
    fused_agg1_kernel<<<NBUCK, TPB, 0, stream>>>(part1, bktBase, bktTot, x, W1,
                                                 deg, off, h1, accum);
    bnparams_kernel<<<1, 64, 0, stream>>>(accum, gamma1, beta1, params, 2,
                                          1.0f / (float)N);
    agg2_kernel<<<NBUCK, TPB, 0, stream>>>(part1, bktBase, bktTot, off, deg,
                                           h1, W2, params, h2, accum + 4);
    bnparams_kernel<<<1, 64, 0, stream>>>(accum + 4, gamma2, beta2, params + 4, 4,
                                          1.0f / (float)N);
    pool_kernel<<<512, 256, 0, stream>>>(h2, pos, params + 4, pooled, N);
    final_kernel<<<1, 64, 0, stream>>>(pooled, fcw, out);
}

// Round 17
// 241.197 us; speedup vs baseline: 1.0932x; 1.0932x over previous
//
#include <hip/hip_runtime.h>

// ---------------------------------------------------------------------------
// net_39041252721195: SplineConv(1->2) + ELU + BN + SplineConv(2->4) + BN
//                     + 4x4 grid max-pool + FC(64->4)
// K=2, DIM=3: pseudo in [0,1) => lo==0, idx==b. Basis weights = trilinear.
//
// Round 27: R26 (256-node buckets) REGRESSED 253.8->263.7: 1024-bin scatter
// paid +12MB WRITE (4-rec runs) + 6KB more LDS; agg gains eaten. Refined
// model: agg occupancy is GRID-capped (512 blocks = 2/CU), not LDS-capped.
// Fix without touching the proven sort: aggs at TPB=512 (8 waves/block ->
// 16 waves/CU) with 2 threads/node (parity-split segment + width-2 shfl
// combine), halving each thread's serial gather chain. Sort side = R25
// verbatim (NBUCK=512). REGN 40->20, scan 1 bin/thread w/ 8-wave fixup.
// ---------------------------------------------------------------------------

#define TPB 256
#define TPA 512                     // threads per agg block
#define NODES_PER_BUCK 512
#define BUCK_SHIFT 9
#define NBUCK 512                   // N / 512 (N = 262144)
#define BPART 512                   // partition blocks for bucket hist/scatter
#define REGN 20                     // records staged per thread (cap 10240/bucket)
#define SCAP1 5120                  // LDS stage cap per half-bucket (16 sd)
#define CHUNK 4096                  // scatter chunk (block owns 8192 = 2 chunks)
#define EPT 16                      // edges per thread per chunk

typedef unsigned long long u64;
typedef unsigned int u32;
typedef unsigned short u16;

__device__ __forceinline__ void basis_weights(float f0, float f1, float f2, float w[8]) {
    float g0 = 1.f - f0, g1 = 1.f - f1, g2 = 1.f - f2;
    w[0] = g0 * g1 * g2;  w[1] = f0 * g1 * g2;
    w[2] = g0 * f1 * g2;  w[3] = f0 * f1 * g2;
    w[4] = g0 * g1 * f2;  w[5] = f0 * g1 * f2;
    w[6] = g0 * f1 * f2;  w[7] = f0 * f1 * f2;
}

__device__ __forceinline__ u64 pack_rec(int src, int dloc, float f0, float f1, float f2) {
    u32 q0 = (u32)(f0 * 4095.f + 0.5f);
    u32 q1 = (u32)(f1 * 4095.f + 0.5f);
    u32 q2 = (u32)(f2 * 4095.f + 0.5f);
    return (u64)(u32)src | ((u64)(u32)dloc << 18)
         | ((u64)q0 << 27) | ((u64)q1 << 39) | ((u64)q2 << 51);
}

// ---- exclusive scan over 256 threads (2 bins/thread upstream) --------------
__device__ __forceinline__ u32 scan_shfl(u32 tsum, u32* wtot, int t) {
    u32 incl = tsum;
#pragma unroll
    for (int o = 1; o < 64; o <<= 1) {
        u32 v = __shfl_up(incl, o, 64);
        if ((t & 63) >= o) incl += v;
    }
    if ((t & 63) == 63) wtot[t >> 6] = incl;
    __syncthreads();
    u32 wbase = 0;
#pragma unroll
    for (int w = 0; w < 4; w++) wbase += (w < (t >> 6)) ? wtot[w] : 0u;
    return wbase + incl - tsum;
}

// ---- exclusive scan over 512 threads (1 bin/thread, 8-wave fixup) ----------
__device__ __forceinline__ u32 scanT_shfl(u32 tsum, u32* wtot, int t) {
    u32 incl = tsum;
#pragma unroll
    for (int o = 1; o < 64; o <<= 1) {
        u32 v = __shfl_up(incl, o, 64);
        if ((t & 63) >= o) incl += v;
    }
    if ((t & 63) == 63) wtot[t >> 6] = incl;
    __syncthreads();
    u32 wbase = 0;
#pragma unroll
    for (int w = 0; w < 8; w++) wbase += (w < (t >> 6)) ? wtot[w] : 0u;
    return wbase + incl - tsum;
}

// ---- bucket sort pass 1: per-block LDS histogram of dst>>9 (R10-proven) ----
__global__ void hist_kernel(const int* __restrict__ ei, int E,
                            u32* __restrict__ cntArr /* [NBUCK][BPART] */) {
    __shared__ u32 h[NBUCK];
    for (int i = threadIdx.x; i < NBUCK; i += TPB) h[i] = 0u;
    __syncthreads();
    int ch = (E + BPART - 1) / BPART;
    int s = blockIdx.x * ch;
    int e_end = min(E, s + ch);
    int e = s + threadIdx.x * 4;
    for (; e + 4 <= e_end; e += TPB * 4) {
        int4 d4 = *(const int4*)&ei[E + e];
        atomicAdd(&h[d4.x >> BUCK_SHIFT], 1u);
        atomicAdd(&h[d4.y >> BUCK_SHIFT], 1u);
        atomicAdd(&h[d4.z >> BUCK_SHIFT], 1u);
        atomicAdd(&h[d4.w >> BUCK_SHIFT], 1u);
    }
    for (e = e_end - (e_end - s) % (TPB * 4) + threadIdx.x; e < e_end; e += TPB)
        atomicAdd(&h[ei[E + e] >> BUCK_SHIFT], 1u);
    __syncthreads();
    for (int i = threadIdx.x; i < NBUCK; i += TPB)
        cntArr[i * BPART + blockIdx.x] = h[i];
}

// ---- scan: per-bucket exclusive prefix over BPART values, IN PLACE ---------
__global__ void scan512_kernel(u32* __restrict__ data,
                               u32* __restrict__ totals) {
    __shared__ u32 s[BPART];
    int t = threadIdx.x, g = blockIdx.x;
    u32 v = data[g * BPART + t];
    s[t] = v;
    __syncthreads();
    for (int o = 1; o < BPART; o <<= 1) {
        u32 u = (t >= o) ? s[t - o] : 0u;
        __syncthreads();
        s[t] += u;
        __syncthreads();
    }
    data[g * BPART + t] = s[t] - v;     // exclusive
    if (t == BPART - 1) totals[g] = s[t];
}

// ---- scan of NBUCK bucket totals -> bucket bases ---------------------------
__global__ void scanbase_kernel(const u32* __restrict__ in,   // [NBUCK]
                                u32* __restrict__ excl) {     // [NBUCK]
    __shared__ u32 s[NBUCK];
    int t = threadIdx.x;
    u32 v = in[t];
    s[t] = v;
    __syncthreads();
    for (int o = 1; o < NBUCK; o <<= 1) {
        u32 u = (t >= o) ? s[t - o] : 0u;
        __syncthreads();
        s[t] += u;
        __syncthreads();
    }
    excl[t] = s[t] - v;
}

// ---- scatter: chunk-local LDS counting sort -> coalesced stream writes -----
__global__ void __launch_bounds__(TPB)
scatter_kernel(const int* __restrict__ ei,
               const float* __restrict__ attr,
               const u32* __restrict__ bktBase,
               const u32* __restrict__ preArr,
               u64* __restrict__ part1, int E) {
    __shared__ u64 stage[CHUNK];          // 32 KB bucket-grouped records
    __shared__ u16 bid[CHUNK];            // 8 KB bucket id per stage slot
    __shared__ u32 cnt[NBUCK];            // 2 KB per-chunk counts
    __shared__ u32 cbase[NBUCK];          // 2 KB chunk-local bucket bases
    __shared__ u32 gcur[NBUCK];           // 2 KB global cursors
    __shared__ u32 wtot[4];               // wave totals for shfl scan
    int t = threadIdx.x, blk = blockIdx.x;
    for (int i = t; i < NBUCK; i += TPB)
        gcur[i] = bktBase[i] + preArr[i * BPART + blk];
    int ch = (E + BPART - 1) / BPART;     // 8192
    int s0 = blk * ch;
    int e_end = min(E, s0 + ch);
    for (int cs = s0; cs < e_end; cs += CHUNK) {
        int cn = min(CHUNK, e_end - cs);
        cnt[t] = 0u; cnt[t + TPB] = 0u;
        __syncthreads();
        // pass A: vectorized load+pack (4 edges per k-step), rank via LDS atomic
        u64 rec[EPT]; u32 bb[EPT], rk[EPT];
#pragma unroll
        for (int k = 0; k < 4; k++) {
            int e = cs + k * (TPB * 4) + t * 4;
            if (e + 3 < e_end) {
                int4 s4 = *(const int4*)&ei[e];
                int4 d4 = *(const int4*)&ei[E + e];
                float4 a0 = *(const float4*)&attr[3 * e];
                float4 a1 = *(const float4*)&attr[3 * e + 4];
                float4 a2 = *(const float4*)&attr[3 * e + 8];
                int srcs[4] = {s4.x, s4.y, s4.z, s4.w};
                int dsts[4] = {d4.x, d4.y, d4.z, d4.w};
                float f[4][3] = {{a0.x, a0.y, a0.z}, {a0.w, a1.x, a1.y},
                                 {a1.z, a1.w, a2.x}, {a2.y, a2.z, a2.w}};
#pragma unroll
                for (int j = 0; j < 4; j++) {
                    int m = 4 * k + j;
                    rec[m] = pack_rec(srcs[j], dsts[j] & (NODES_PER_BUCK - 1),
                                      f[j][0], f[j][1], f[j][2]);
                    bb[m] = (u32)dsts[j] >> BUCK_SHIFT;
                    rk[m] = atomicAdd(&cnt[bb[m]], 1u);
                }
            } else {
#pragma unroll
                for (int j = 0; j < 4; j++) {
                    int m = 4 * k + j;
                    int ee = e + j;
                    bb[m] = 0xFFFFFFFFu;
                    if (ee < e_end) {
                        rec[m] = pack_rec(ei[ee], ei[E + ee] & (NODES_PER_BUCK - 1),
                                          attr[3 * ee], attr[3 * ee + 1],
                                          attr[3 * ee + 2]);
                        bb[m] = (u32)ei[E + ee] >> BUCK_SHIFT;
                        rk[m] = atomicAdd(&cnt[bb[m]], 1u);
                    }
                }
            }
        }
        __syncthreads();
        // shfl scan of 512 counts -> chunk-local bases
        u32 c0 = cnt[2 * t], c1 = cnt[2 * t + 1];
        u32 ex = scan_shfl(c0 + c1, wtot, t);
        cbase[2 * t] = ex;
        cbase[2 * t + 1] = ex + c0;
        __syncthreads();
        // pass B: LDS scatter into bucket-grouped order
#pragma unroll
        for (int m = 0; m < EPT; m++) {
            if (bb[m] != 0xFFFFFFFFu) {
                u32 p = cbase[bb[m]] + rk[m];
                stage[p] = rec[m];
                bid[p] = (u16)bb[m];
            }
        }
        __syncthreads();
        // pass C: i-ordered write-out -> contiguous bursts per bucket run
        for (int i = t; i < cn; i += TPB) {
            u32 b = (u32)bid[i];
            part1[gcur[b] + ((u32)i - cbase[b])] = stage[i];
        }
        __syncthreads();
        // pass D: advance cursors
        gcur[2 * t] += c0;
        gcur[2 * t + 1] += c1;
        __syncthreads();
    }
}

// ---- layer 1: TPA=512 threads, 2 threads/node, factorized inner loop -------
__global__ void __launch_bounds__(TPA)
fused_agg1_kernel(const u64* __restrict__ part1,
                  const u32* __restrict__ bktBase,
                  const u32* __restrict__ bktTot,
                  const float* __restrict__ x,
                  const float* __restrict__ W1,      // [8][1][2] = 16 floats
                  u32* __restrict__ deg,
                  u32* __restrict__ off,
                  float* __restrict__ h1,
                  float* __restrict__ accum /* sum[2], sq[2] */) {
    __shared__ u64 stage[SCAP1];           // 40 KB node-ordered half-window
    __shared__ u32 hist[NODES_PER_BUCK];   // counts -> LOCAL cursors (2KB)
    __shared__ u32 obase[NODES_PER_BUCK];  // LOCAL segment starts (2KB)
    __shared__ u32 wtot[8];
    __shared__ u32 midsh;
    __shared__ float rbuf[8][4];
    int t = threadIdx.x, g = blockIdx.x;
    u32 s = bktBase[g], n_e = bktTot[g];
    if (n_e > (u32)(REGN * TPA)) n_e = (u32)(REGN * TPA);
    hist[t < NODES_PER_BUCK ? t : 0] = 0u;   // t<512 always true; plain init:
    __syncthreads();                          // (kept simple: one store each)
    // register staging: one coalesced read of the bucket window
    u64 rec[REGN];
#pragma unroll
    for (int k = 0; k < REGN; k++) {
        u32 i = (u32)t + (u32)k * TPA;
        rec[k] = (i < n_e) ? part1[s + i] : 0ull;
    }
    // count local node ids (from registers)
#pragma unroll
    for (int k = 0; k < REGN; k++) {
        u32 i = (u32)t + (u32)k * TPA;
        if (i < n_e)
            atomicAdd(&hist[(u32)(rec[k] >> 18) & (NODES_PER_BUCK - 1)], 1u);
    }
    __syncthreads();
    // scan 512 counts (1 bin/thread) -> LOCAL offsets
    u32 c = hist[t];
    u32 ex = scanT_shfl(c, wtot, t);
    obase[t] = ex;
    int n0 = (g << BUCK_SHIFT) + t;
    deg[n0] = c; off[n0] = s + ex;
    hist[t] = ex;                          // local cursor
    if (t == 256) midsh = ex;              // records in bins 0..255
    __syncthreads();
    u32 mid = midsh;
    float ts0 = 0.f, ts1 = 0.f, tq0 = 0.f, tq1 = 0.f;
    for (int h = 0; h < 2; h++) {
        u32 pstart = h ? mid : 0u;
        u32 plen = h ? (n_e - mid) : mid;
        if (plen > (u32)SCAP1) plen = (u32)SCAP1;
        // rescatter phase-h records from registers into LDS stage
#pragma unroll
        for (int k = 0; k < REGN; k++) {
            u32 i = (u32)t + (u32)k * TPA;
            if (i < n_e) {
                u32 loc = (u32)(rec[k] >> 18) & (NODES_PER_BUCK - 1);
                if ((int)(loc >> 8) == h) {
                    u32 pos = atomicAdd(&hist[loc], 1u);
                    u32 li = pos - pstart;
                    if (li < (u32)SCAP1) stage[li] = rec[k];
                }
            }
        }
        __syncthreads();
        // aggregate: 2 threads per node, parity split
        int ln = h * 256 + (t >> 1);
        int sub = t & 1;
        u32 st = obase[ln] - pstart;
        u32 en = hist[ln] - pstart;        // cursor = local segment end
        u32 d = hist[ln] - obase[ln];      // true degree
        if (en > plen) en = plen;
        if (st > plen) st = plen;
        float S[8];
#pragma unroll
        for (int b = 0; b < 8; b++) S[b] = 0.f;
        for (u32 j = st + (u32)sub; j < en; j += 2) {
            u64 r = stage[j];
            float xv = x[(u32)r & 0x3FFFFu];
            float f0 = (float)((u32)(r >> 27) & 0xFFFu) * (1.f / 4095.f);
            float f1 = (float)((u32)(r >> 39) & 0xFFFu) * (1.f / 4095.f);
            float f2 = (float)((u32)(r >> 51) & 0xFFFu) * (1.f / 4095.f);
            float w[8];
            basis_weights(f0, f1, f2, w);
#pragma unroll
            for (int b = 0; b < 8; b++) S[b] += w[b] * xv;
        }
        // width-2 combine: sub 0 gets the node total
#pragma unroll
        for (int b = 0; b < 8; b++) S[b] += __shfl_down(S[b], 1, 2);
        if (sub == 0) {
            float s0 = 0.f, s1 = 0.f;
#pragma unroll
            for (int b = 0; b < 8; b++) {
                s0 += S[b] * W1[2 * b];
                s1 += S[b] * W1[2 * b + 1];
            }
            float cm = d > 1u ? (float)d : 1.f;
            float a = s0 / cm, b2 = s1 / cm;
            a = a > 0.f ? a : (__expf(a) - 1.f);   // ELU
            b2 = b2 > 0.f ? b2 : (__expf(b2) - 1.f);
            int n = (g << BUCK_SHIFT) + ln;
            *(float2*)&h1[2 * n] = make_float2(a, b2);
            ts0 += a; tq0 += a * a;
            ts1 += b2; tq1 += b2 * b2;
        }
        __syncthreads();                   // stage reused next phase
    }
#pragma unroll
    for (int o = 32; o > 0; o >>= 1) {
        ts0 += __shfl_down(ts0, o, 64);
        ts1 += __shfl_down(ts1, o, 64);
        tq0 += __shfl_down(tq0, o, 64);
        tq1 += __shfl_down(tq1, o, 64);
    }
    int wv = t >> 6;
    if ((t & 63) == 0) {
        rbuf[wv][0] = ts0; rbuf[wv][1] = ts1;
        rbuf[wv][2] = tq0; rbuf[wv][3] = tq1;
    }
    __syncthreads();
    if (t < 4) {
        float v = 0.f;
#pragma unroll
        for (int w = 0; w < 8; w++) v += rbuf[w][t];
        atomicAdd(&accum[t], v);
    }
}

// ---- BN params: scale = gamma*rsqrt(var+eps); shift = beta - mu*scale ------
__global__ void bnparams_kernel(const float* __restrict__ accum,
                                const float* __restrict__ gamma,
                                const float* __restrict__ beta,
                                float* __restrict__ params, int C, float invN) {
    int c = threadIdx.x;
    if (c < C) {
        float mu  = accum[c] * invN;
        float var = accum[C + c] * invN - mu * mu;
        float sc  = gamma[c] * rsqrtf(var + 1e-5f);
        params[c] = sc;
        params[C + c] = beta[c] - mu * sc;
    }
}

// ---- layer 2: TPA=512 threads, 2 threads/node, factorized inner loop -------
__global__ void __launch_bounds__(TPA)
agg2_kernel(const u64* __restrict__ part1,
            const u32* __restrict__ bktBase,
            const u32* __restrict__ bktTot,
            const u32* __restrict__ off,
            const u32* __restrict__ deg,
            const float* __restrict__ h1,
            const float* __restrict__ W2,        // [8][2][4] = 64 floats
            const float* __restrict__ params,    // sc1[2], sh1[2]
            float* __restrict__ h2,
            float* __restrict__ accum /* sum[4], sq[4] */) {
    __shared__ u64 stage[SCAP1];            // 40 KB
    __shared__ u32 hist[NODES_PER_BUCK];    // local cursors (2KB)
    __shared__ u32 obase[NODES_PER_BUCK];   // local starts (2KB)
    __shared__ u32 segend[NODES_PER_BUCK];  // local ends (2KB)
    __shared__ float rbuf[8][8];
    int t = threadIdx.x, g = blockIdx.x;
    u32 s = bktBase[g], n_e = bktTot[g];
    if (n_e > (u32)(REGN * TPA)) n_e = (u32)(REGN * TPA);
    int nb = (g << BUCK_SHIFT);
    {
        u32 o = off[nb + t] - s;           // local
        u32 dd = deg[nb + t];
        obase[t] = o;
        segend[t] = o + dd;
        hist[t] = o;                       // cursor init
    }
    // register staging: one coalesced read
    u64 rec[REGN];
#pragma unroll
    for (int k = 0; k < REGN; k++) {
        u32 i = (u32)t + (u32)k * TPA;
        rec[k] = (i < n_e) ? part1[s + i] : 0ull;
    }
    float sc0 = params[0], sc1 = params[1], sh0 = params[2], sh1 = params[3];
    __syncthreads();
    u32 mid = obase[256];
    float ts[4] = {0.f, 0.f, 0.f, 0.f}, tq[4] = {0.f, 0.f, 0.f, 0.f};
    for (int h = 0; h < 2; h++) {
        u32 pstart = h ? mid : 0u;
        u32 plen = h ? (n_e - mid) : mid;
        if (plen > (u32)SCAP1) plen = (u32)SCAP1;
#pragma unroll
        for (int k = 0; k < REGN; k++) {
            u32 i = (u32)t + (u32)k * TPA;
            if (i < n_e) {
                u32 loc = (u32)(rec[k] >> 18) & (NODES_PER_BUCK - 1);
                if ((int)(loc >> 8) == h) {
                    u32 pos = atomicAdd(&hist[loc], 1u);
                    u32 li = pos - pstart;
                    if (li < (u32)SCAP1) stage[li] = rec[k];
                }
            }
        }
        __syncthreads();
        int ln = h * 256 + (t >> 1);
        int sub = t & 1;
        u32 st = obase[ln] - pstart;
        u32 en = segend[ln] - pstart;
        u32 d = segend[ln] - obase[ln];
        if (en > plen) en = plen;
        if (st > plen) st = plen;
        float Sa[8], Sb[8];
#pragma unroll
        for (int b = 0; b < 8; b++) { Sa[b] = 0.f; Sb[b] = 0.f; }
        for (u32 j = st + (u32)sub; j < en; j += 2) {
            u64 r = stage[j];
            float2 hv = *(const float2*)&h1[2 * ((u32)r & 0x3FFFFu)];
            float a = hv.x * sc0 + sh0;
            float b = hv.y * sc1 + sh1;
            float f0 = (float)((u32)(r >> 27) & 0xFFFu) * (1.f / 4095.f);
            float f1 = (float)((u32)(r >> 39) & 0xFFFu) * (1.f / 4095.f);
            float f2 = (float)((u32)(r >> 51) & 0xFFFu) * (1.f / 4095.f);
            float w[8];
            basis_weights(f0, f1, f2, w);
#pragma unroll
            for (int bb = 0; bb < 8; bb++) {
                Sa[bb] += w[bb] * a;
                Sb[bb] += w[bb] * b;
            }
        }
#pragma unroll
        for (int b = 0; b < 8; b++) {
            Sa[b] += __shfl_down(Sa[b], 1, 2);
            Sb[b] += __shfl_down(Sb[b], 1, 2);
        }
        if (sub == 0) {
            float m0 = 0.f, m1 = 0.f, m2 = 0.f, m3 = 0.f;
#pragma unroll
            for (int bb = 0; bb < 8; bb++) {
                m0 += Sa[bb] * W2[8 * bb + 0] + Sb[bb] * W2[8 * bb + 4];
                m1 += Sa[bb] * W2[8 * bb + 1] + Sb[bb] * W2[8 * bb + 5];
                m2 += Sa[bb] * W2[8 * bb + 2] + Sb[bb] * W2[8 * bb + 6];
                m3 += Sa[bb] * W2[8 * bb + 3] + Sb[bb] * W2[8 * bb + 7];
            }
            float cm = d > 1u ? (float)d : 1.f;
            m0 /= cm; m1 /= cm; m2 /= cm; m3 /= cm;
            int n = nb + ln;
            float4 o4; o4.x = m0; o4.y = m1; o4.z = m2; o4.w = m3;
            *(float4*)&h2[4 * n] = o4;
            ts[0] += m0; tq[0] += m0 * m0;
            ts[1] += m1; tq[1] += m1 * m1;
            ts[2] += m2; tq[2] += m2 * m2;
            ts[3] += m3; tq[3] += m3 * m3;
        }
        __syncthreads();                   // stage reused next phase
    }
#pragma unroll
    for (int o = 32; o > 0; o >>= 1) {
#pragma unroll
        for (int ch = 0; ch < 4; ch++) {
            ts[ch] += __shfl_down(ts[ch], o, 64);
            tq[ch] += __shfl_down(tq[ch], o, 64);
        }
    }
    int wv = t >> 6;
    if ((t & 63) == 0) {
#pragma unroll
        for (int ch = 0; ch < 4; ch++) {
            rbuf[wv][ch] = ts[ch];
            rbuf[wv][4 + ch] = tq[ch];
        }
    }
    __syncthreads();
    if (t < 8) {
        float v = 0.f;
#pragma unroll
        for (int w = 0; w < 8; w++) v += rbuf[w][t];
        atomicAdd(&accum[t], v);
    }
}

// ---- pooling: BN2 normalize, grid cluster, ordered-uint atomicMax ----------
__device__ __forceinline__ unsigned enc_float(float v) {
    unsigned u = __float_as_uint(v);
    return (v >= 0.f) ? (u | 0x80000000u) : ~u;
}

__global__ void pool_kernel(const float* __restrict__ h2,
                            const float* __restrict__ pos,
                            const float* __restrict__ params, // scale2[4], shift2[4]
                            unsigned* __restrict__ pooled, int N) {
    __shared__ unsigned lmax[64];
    for (int i = threadIdx.x; i < 64; i += blockDim.x) lmax[i] = 0u;
    __syncthreads();
    float sc[4], sh[4];
#pragma unroll
    for (int c = 0; c < 4; c++) { sc[c] = params[c]; sh[c] = params[4 + c]; }
    int stride = gridDim.x * blockDim.x;
    for (int n = blockIdx.x * blockDim.x + threadIdx.x; n < N; n += stride) {
        float px = pos[2 * n + 0], py = pos[2 * n + 1];
        int cx = (int)floorf(px * (1.f / 25.f));
        int cy = (int)floorf(py * (1.f / 25.f));
        cx = min(max(cx, 0), 3);
        cy = min(max(cy, 0), 3);
        int cl = cx + 4 * cy;
        float4 h = *(const float4*)&h2[4 * n];
        atomicMax(&lmax[4 * cl + 0], enc_float(h.x * sc[0] + sh[0]));
        atomicMax(&lmax[4 * cl + 1], enc_float(h.y * sc[1] + sh[1]));
        atomicMax(&lmax[4 * cl + 2], enc_float(h.z * sc[2] + sh[2]));
        atomicMax(&lmax[4 * cl + 3], enc_float(h.w * sc[3] + sh[3]));
    }
    __syncthreads();
    for (int i = threadIdx.x; i < 64; i += blockDim.x)
        if (lmax[i]) atomicMax(&pooled[i], lmax[i]);
}

// ---- final: decode pooled, FC 64->4 ----------------------------------------
__global__ void final_kernel(const unsigned* __restrict__ pooled,
                             const float* __restrict__ fcw, // [4][64]
                             float* __restrict__ out) {
    __shared__ float p[64];
    int t = threadIdx.x;
    if (t < 64) {
        unsigned u = pooled[t];
        float v = 0.f;
        if (u != 0u) {
            unsigned bits = (u & 0x80000000u) ? (u ^ 0x80000000u) : ~u;
            v = __uint_as_float(bits);
        }
        p[t] = v;
    }
    __syncthreads();
    if (t < 4) {
        float s = 0.f;
        for (int k = 0; k < 64; k++) s += p[k] * fcw[t * 64 + k];
        out[t] = s;
    }
}

// ---------------------------------------------------------------------------
extern "C" void kernel_launch(void* const* d_in, const int* in_sizes, int n_in,
                              void* d_out, int out_size, void* d_ws, size_t ws_size,
                              hipStream_t stream) {
    const float* x      = (const float*)d_in[0];
    const int*   ei     = (const int*)d_in[1];
    const float* attr   = (const float*)d_in[2];
    const float* pos    = (const float*)d_in[3];
    const float* W1     = (const float*)d_in[4];
    const float* W2     = (const float*)d_in[5];
    const float* gamma1 = (const float*)d_in[6];
    const float* beta1  = (const float*)d_in[7];
    const float* gamma2 = (const float*)d_in[8];
    const float* beta2  = (const float*)d_in[9];
    const float* fcw    = (const float*)d_in[10];
    float* out = (float*)d_out;

    const int N = in_sizes[0];       // 262144 = 512*512
    const int E = in_sizes[2] / 3;   // 4194304

    // workspace layout (~43 MB)
    u64* part1 = (u64*)d_ws;                             // E packed records (bucket order)
    float* base = (float*)(part1 + E);
    float* accum  = base;                                // 12
    float* params = base + 12;                           // 12
    unsigned* pooled = (unsigned*)(base + 24);           // 64
    u32* cntArr  = (u32*)(base + 88);                    // NBUCK*BPART (scanned in place)
    u32* bktTot  = cntArr + (size_t)NBUCK * BPART;       // NBUCK
    u32* bktBase = bktTot + NBUCK;                       // NBUCK
    u32* deg     = bktBase + NBUCK;                      // N
    u32* off     = deg + N;                              // N (global CSR offsets)
    float* h1 = (float*)(off + N);                       // 2N
    float* h2 = h1 + 2 * (size_t)N;                      // 4N

    hipMemsetAsync(base, 0, 88 * sizeof(float), stream);

    hist_kernel<<<BPART, TPB, 0, stream>>>(ei, E, cntArr);
    scan512_kernel<<<NBUCK, BPART, 0, stream>>>(cntArr, bktTot);
    scanbase_kernel<<<1, NBUCK, 0, stream>>>(bktTot, bktBase);
    scatter_kernel<<<BPART, TPB, 0, stream>>>(ei, attr, bktBase, cntArr, part1, E);
    fused_agg1_kernel<<<NBUCK, TPA, 0, stream>>>(part1, bktBase, bktTot, x, W1,
                                                 deg, off, h1, accum);
    bnparams_kernel<<<1, 64, 0, stream>>>(accum, gamma1, beta1, params, 2,
                                          1.0f / (float)N);
    agg2_kernel<<<NBUCK, TPA, 0, stream>>>(part1, bktBase, bktTot, off, deg,
                                           h1, W2, params, h2, accum + 4);
    bnparams_kernel<<<1, 64, 0, stream>>>(accum + 4, gamma2, beta2, params + 4, 4,
                                          1.0f / (float)N);
    pool_kernel<<<512, 256, 0, stream>>>(h2, pos, params + 4, pooled, N);
    final_kernel<<<1, 64, 0, stream>>>(pooled, fcw, out);
}